// Round 1
// baseline (771.939 us; speedup 1.0000x reference)
//
#include <hip/hip_runtime.h>
#include <hip/hip_bf16.h>

#define N_SRC_C 100000
#define E_TOT   300000
#define D_DIM   256
#define N_EXP   5
#define BM      128
#define LDK     264   // 256 + 8 bf16 pad: keeps 16B alignment, breaks pow2 bank stride
#define MAX_TILES ((E_TOT + BM - 1) / BM + N_EXP)

typedef __attribute__((ext_vector_type(8))) short bf16x8;
typedef __attribute__((ext_vector_type(4))) float f32x4;

// ws header layout (ints): [0..4] hist, [5] mask byte-sum, [11..15] cursors
// perm[] at byte offset 1024

__device__ inline unsigned short f2bf(float f) {
  union { float f; unsigned u; } v; v.f = f;
  unsigned u = v.u;
  u += 0x7FFFu + ((u >> 16) & 1u);   // round-to-nearest-even
  return (unsigned short)(u >> 16);
}

__global__ void detect_kernel(const unsigned int* __restrict__ m32, int* __restrict__ hdr) {
  int tid = blockIdx.x * blockDim.x + threadIdx.x;
  const int n = (N_EXP * E_TOT) / 4;  // 375000 words = 1.5MB, safe under both layouts
  unsigned s = 0;
  for (int i = tid; i < n; i += gridDim.x * blockDim.x) {
    unsigned v = m32[i];
    s += (v & 0xFFu) + ((v >> 8) & 0xFFu) + ((v >> 16) & 0xFFu) + ((v >> 24) & 0xFFu);
  }
  for (int o = 32; o > 0; o >>= 1) s += __shfl_down(s, o);
  if ((threadIdx.x & 63) == 0 && s) atomicAdd(&hdr[5], (int)s);
}

__device__ inline int get_expert(const void* masks, int e, bool is_u8) {
  if (is_u8) {
    const unsigned char* m = (const unsigned char*)masks;
#pragma unroll
    for (int i = 0; i < N_EXP; ++i) if (m[(size_t)i * E_TOT + e]) return i;
  } else {
    const int* m = (const int*)masks;
#pragma unroll
    for (int i = 0; i < N_EXP; ++i) if (m[(size_t)i * E_TOT + e]) return i;
  }
  return 0;
}

__global__ void hist_kernel(const void* __restrict__ masks, int* __restrict__ hdr) {
  __shared__ int h[N_EXP];
  if (threadIdx.x < N_EXP) h[threadIdx.x] = 0;
  __syncthreads();
  bool is_u8 = (hdr[5] == E_TOT);
  int e = blockIdx.x * blockDim.x + threadIdx.x;
  if (e < E_TOT) atomicAdd(&h[get_expert(masks, e, is_u8)], 1);
  __syncthreads();
  if (threadIdx.x < N_EXP) atomicAdd(&hdr[threadIdx.x], h[threadIdx.x]);
}

__global__ void offsets_kernel(int* hdr) {
  int run = 0;
  for (int i = 0; i < N_EXP; ++i) {
    hdr[11 + i] = run;   // cursors start at bucket offsets
    run += hdr[i];
  }
}

__global__ void scatter_kernel(const void* __restrict__ masks, int* __restrict__ hdr,
                               int* __restrict__ perm) {
  __shared__ int lc[N_EXP];
  __shared__ int base[N_EXP];
  if (threadIdx.x < N_EXP) lc[threadIdx.x] = 0;
  __syncthreads();
  bool is_u8 = (hdr[5] == E_TOT);
  int e = blockIdx.x * blockDim.x + threadIdx.x;
  int ex = 0, r = 0;
  bool valid = (e < E_TOT);
  if (valid) { ex = get_expert(masks, e, is_u8); r = atomicAdd(&lc[ex], 1); }
  __syncthreads();
  if (threadIdx.x < N_EXP) base[threadIdx.x] = atomicAdd(&hdr[11 + threadIdx.x], lc[threadIdx.x]);
  __syncthreads();
  if (valid) perm[base[ex] + r] = e;
}

__launch_bounds__(256)
__global__ void gemm_kernel(const float* __restrict__ x, const float* __restrict__ W,
                            const float* __restrict__ bias, const int* __restrict__ index,
                            const int* __restrict__ hdr, const int* __restrict__ perm,
                            float* __restrict__ out) {
  __shared__ __align__(16) unsigned short lA[BM * LDK];   // 67.5 KB
  __shared__ __align__(16) unsigned short lB[128 * LDK];  // 67.5 KB
  __shared__ int srcRow[BM];
  __shared__ int outRow[BM];

  // block -> (expert, row-tile)
  int t = (int)blockIdx.x;
  int ex = -1, trow = 0, off = 0, cnt = 0, accT = 0, run = 0;
#pragma unroll
  for (int i = 0; i < N_EXP; ++i) {
    int c = hdr[i];
    int nt = (c + BM - 1) / BM;
    if (ex < 0 && t < accT + nt) { ex = i; trow = t - accT; cnt = c; off = run; }
    accT += nt; run += c;
  }
  if (ex < 0) return;
  int row0 = off + trow * BM;
  int rows = min(BM, cnt - trow * BM);

  const int tt = threadIdx.x;
  if (tt < BM) {
    int rr = min(tt, rows - 1);       // clamp tail: duplicate last valid row (masked at store)
    int e = perm[row0 + rr];
    outRow[tt] = e;
    srcRow[tt] = index[e];
  }
  __syncthreads();

  // stage A: gather 128 rows x 256 f32 -> bf16 LDS  (one wave covers one row per iter)
  for (int i = 0; i < 32; ++i) {
    int lin = i * 256 + tt;
    int r = lin >> 6;
    int c4 = lin & 63;
    const float4 v = ((const float4*)(x + (size_t)srcRow[r] * D_DIM))[c4];
    ushort4 o;
    o.x = f2bf(v.x); o.y = f2bf(v.y); o.z = f2bf(v.z); o.w = f2bf(v.w);
    *(ushort4*)&lA[r * LDK + c4 * 4] = o;
  }

  const int w = tt >> 6, lane = tt & 63, quad = lane >> 4, l16 = lane & 15;

  for (int h = 0; h < 2; ++h) {
    __syncthreads();   // protect lB reuse across halves
    // stage B half: W[ex][h*128 + n][k]  (W row-major [n][k] == B^T, same frag path as A)
    const float* wb = W + ((size_t)ex * D_DIM + h * 128) * D_DIM;
    for (int i = 0; i < 32; ++i) {
      int lin = i * 256 + tt;
      int r = lin >> 6;
      int c4 = lin & 63;
      const float4 v = ((const float4*)(wb + (size_t)r * D_DIM))[c4];
      ushort4 o;
      o.x = f2bf(v.x); o.y = f2bf(v.y); o.z = f2bf(v.z); o.w = f2bf(v.w);
      *(ushort4*)&lB[r * LDK + c4 * 4] = o;
    }
    __syncthreads();

    f32x4 acc[2][8];
#pragma unroll
    for (int mt = 0; mt < 2; ++mt)
#pragma unroll
      for (int nt = 0; nt < 8; ++nt)
        acc[mt][nt] = (f32x4){0.f, 0.f, 0.f, 0.f};

#pragma unroll
    for (int ks = 0; ks < 8; ++ks) {
      int k0 = ks * 32 + quad * 8;
      bf16x8 a[2], bfr[8];
#pragma unroll
      for (int mt = 0; mt < 2; ++mt)
        a[mt] = *(const bf16x8*)&lA[(w * 32 + mt * 16 + l16) * LDK + k0];
#pragma unroll
      for (int nt = 0; nt < 8; ++nt)
        bfr[nt] = *(const bf16x8*)&lB[(nt * 16 + l16) * LDK + k0];
#pragma unroll
      for (int mt = 0; mt < 2; ++mt)
#pragma unroll
        for (int nt = 0; nt < 8; ++nt)
          acc[mt][nt] = __builtin_amdgcn_mfma_f32_16x16x32_bf16(a[mt], bfr[nt], acc[mt][nt], 0, 0, 0);
    }

    // epilogue: C/D layout col=lane&15, row=quad*4+reg (m89-verified); scatter rows via perm
#pragma unroll
    for (int nt = 0; nt < 8; ++nt) {
      int col = h * 128 + nt * 16 + l16;
      float bv = bias[ex * D_DIM + col];
#pragma unroll
      for (int mt = 0; mt < 2; ++mt) {
#pragma unroll
        for (int r = 0; r < 4; ++r) {
          int rl = w * 32 + mt * 16 + quad * 4 + r;
          if (rl < rows) {
            int e = outRow[rl];
            out[(size_t)e * D_DIM + col] = acc[mt][nt][r] + bv;
          }
        }
      }
    }
  }
}

extern "C" void kernel_launch(void* const* d_in, const int* in_sizes, int n_in,
                              void* d_out, int out_size, void* d_ws, size_t ws_size,
                              hipStream_t stream) {
  const float* x     = (const float*)d_in[0];
  const float* W     = (const float*)d_in[1];
  const float* bias  = (const float*)d_in[2];
  const int*   index = (const int*)d_in[3];
  const void*  masks = d_in[4];
  float* out = (float*)d_out;

  int* hdr  = (int*)d_ws;
  int* perm = (int*)((char*)d_ws + 1024);

  hipMemsetAsync(d_ws, 0, 1024, stream);
  detect_kernel<<<256, 256, 0, stream>>>((const unsigned int*)masks, hdr);
  int nb = (E_TOT + 255) / 256;
  hist_kernel<<<nb, 256, 0, stream>>>(masks, hdr);
  offsets_kernel<<<1, 1, 0, stream>>>(hdr);
  scatter_kernel<<<nb, 256, 0, stream>>>(masks, hdr, perm);
  gemm_kernel<<<MAX_TILES, 256, 0, stream>>>(x, W, bias, index, hdr, perm, out);
}

// Round 2
// 549.553 us; speedup vs baseline: 1.4047x; 1.4047x over previous
//
#include <hip/hip_runtime.h>
#include <hip/hip_bf16.h>

#define E_TOT   300000
#define D_DIM   256
#define N_EXP   5
#define BM      64
#define LDK     264           // 256 + 8 bf16 pad (2-way bank alias only — free per m136)
#define NB_CNT  ((E_TOT + 255) / 256)          // 1172
#define MAX_TILES (E_TOT / BM + N_EXP)         // 4697
#define CHUNK   8
#define NCHUNK  ((NB_CNT + CHUNK - 1) / CHUNK) // 147

typedef __attribute__((ext_vector_type(8))) short bf16x8;
typedef __attribute__((ext_vector_type(4))) float f32x4;

__device__ inline unsigned short f2bf(float f) {
  union { float f; unsigned u; } v; v.f = f;
  unsigned u = v.u;
  u += 0x7FFFu + ((u >> 16) & 1u);   // round-to-nearest-even
  return (unsigned short)(u >> 16);
}

// ---------- mask layout detect: byte-sum of first 1.5MB == E_TOT iff u8 ----------
__global__ void detect_kernel(const unsigned int* __restrict__ m32, int* __restrict__ hdr) {
  int tid = blockIdx.x * blockDim.x + threadIdx.x;
  const int n = (N_EXP * E_TOT) / 4;
  unsigned s = 0;
  for (int i = tid; i < n; i += gridDim.x * blockDim.x) {
    unsigned v = m32[i];
    s += (v & 0xFFu) + ((v >> 8) & 0xFFu) + ((v >> 16) & 0xFFu) + ((v >> 24) & 0xFFu);
  }
  for (int o = 32; o > 0; o >>= 1) s += __shfl_down(s, o);
  if ((threadIdx.x & 63) == 0 && s) atomicAdd(&hdr[5], (int)s);
}

__device__ inline int get_expert(const void* masks, int e, bool is_u8) {
  if (is_u8) {
    const unsigned char* m = (const unsigned char*)masks;
#pragma unroll
    for (int i = 0; i < N_EXP; ++i) if (m[(size_t)i * E_TOT + e]) return i;
  } else {
    const int* m = (const int*)masks;
#pragma unroll
    for (int i = 0; i < N_EXP; ++i) if (m[(size_t)i * E_TOT + e]) return i;
  }
  return 0;
}

// ---------- atomic-free per-block histogram via ballot ----------
__global__ void count_kernel(const void* __restrict__ masks, const int* __restrict__ hdr,
                             int* __restrict__ blockCounts) {
  __shared__ int wc[4][N_EXP];
  bool is_u8 = (hdr[5] == E_TOT);
  int e = blockIdx.x * blockDim.x + threadIdx.x;
  int ex = (e < E_TOT) ? get_expert(masks, e, is_u8) : -1;
  int w = threadIdx.x >> 6, lane = threadIdx.x & 63;
#pragma unroll
  for (int i = 0; i < N_EXP; ++i) {
    unsigned long long bal = __ballot(ex == i);
    if (lane == 0) wc[w][i] = __popcll(bal);
  }
  __syncthreads();
  if (threadIdx.x < N_EXP)
    blockCounts[blockIdx.x * N_EXP + threadIdx.x] =
        wc[0][threadIdx.x] + wc[1][threadIdx.x] + wc[2][threadIdx.x] + wc[3][threadIdx.x];
}

// ---------- single-block hierarchical scan: block bases + bucket offsets ----------
__global__ void scan_kernel(const int* __restrict__ blockCounts, int* __restrict__ hdr,
                            int* __restrict__ blockBase) {
  __shared__ int cs[NCHUNK][N_EXP];
  __shared__ int cp[NCHUNK][N_EXP];
  int t = threadIdx.x;
  if (t < NCHUNK) {
    int s[N_EXP] = {0, 0, 0, 0, 0};
    int b1 = min((t + 1) * CHUNK, NB_CNT);
    for (int b = t * CHUNK; b < b1; ++b)
#pragma unroll
      for (int i = 0; i < N_EXP; ++i) s[i] += blockCounts[b * N_EXP + i];
#pragma unroll
    for (int i = 0; i < N_EXP; ++i) cs[t][i] = s[i];
  }
  __syncthreads();
  if (t < N_EXP) {
    int run = 0;
    for (int c = 0; c < NCHUNK; ++c) { cp[c][t] = run; run += cs[c][t]; }
    hdr[t] = run;                     // per-expert totals
  }
  __syncthreads();
  if (t == 0) {
    int run = 0;
    for (int i = 0; i < N_EXP; ++i) { hdr[8 + i] = run; run += hdr[i]; }
  }
  __syncthreads();
  if (t < NCHUNK) {
    int r[N_EXP];
#pragma unroll
    for (int i = 0; i < N_EXP; ++i) r[i] = hdr[8 + i] + cp[t][i];
    int b1 = min((t + 1) * CHUNK, NB_CNT);
    for (int b = t * CHUNK; b < b1; ++b)
#pragma unroll
      for (int i = 0; i < N_EXP; ++i) { blockBase[b * N_EXP + i] = r[i]; r[i] += blockCounts[b * N_EXP + i]; }
  }
}

// ---------- deterministic rank-based scatter (zero atomics) ----------
__global__ void scatter_kernel(const void* __restrict__ masks, const int* __restrict__ hdr,
                               const int* __restrict__ blockBase, int* __restrict__ perm) {
  __shared__ int wc[4][N_EXP];
  __shared__ int wo[4][N_EXP];
  __shared__ int bb[N_EXP];
  bool is_u8 = (hdr[5] == E_TOT);
  int e = blockIdx.x * blockDim.x + threadIdx.x;
  int ex = (e < E_TOT) ? get_expert(masks, e, is_u8) : -1;
  int w = threadIdx.x >> 6, lane = threadIdx.x & 63;
  unsigned long long myBal = 0;
#pragma unroll
  for (int i = 0; i < N_EXP; ++i) {
    unsigned long long bal = __ballot(ex == i);
    if (lane == 0) wc[w][i] = __popcll(bal);
    if (ex == i) myBal = bal;
  }
  if (threadIdx.x < N_EXP) bb[threadIdx.x] = blockBase[blockIdx.x * N_EXP + threadIdx.x];
  __syncthreads();
  if (threadIdx.x < 4 * N_EXP) {
    int ww = threadIdx.x / N_EXP, ii = threadIdx.x % N_EXP;
    int s = 0;
    for (int p = 0; p < ww; ++p) s += wc[p][ii];
    wo[ww][ii] = s;
  }
  __syncthreads();
  if (ex >= 0) {
    int rank = __popcll(myBal & ((1ull << lane) - 1ull));
    perm[bb[ex] + wo[w][ex] + rank] = e;
  }
}

// ---------- W fp32 -> bf16 pre-convert ----------
__global__ void convw_kernel(const float* __restrict__ W, unsigned short* __restrict__ Wbf) {
  int i = blockIdx.x * blockDim.x + threadIdx.x;   // 81920 float4s
  float4 v = ((const float4*)W)[i];
  ushort4 o;
  o.x = f2bf(v.x); o.y = f2bf(v.y); o.z = f2bf(v.z); o.w = f2bf(v.w);
  ((ushort4*)Wbf)[i] = o;
}

// ---------- GEMM: BM=64, A-only LDS (4 blocks/CU), B from global bf16 ----------
template <bool PRE>
__launch_bounds__(256, 4)
__global__ void gemm_kernel(const float* __restrict__ x, const float* __restrict__ W,
                            const unsigned short* __restrict__ Wbf,
                            const float* __restrict__ bias, const int* __restrict__ index,
                            const int* __restrict__ hdr, const int* __restrict__ perm,
                            float* __restrict__ out) {
  __shared__ __align__(16) unsigned short lA[BM * LDK];   // 33.75 KB
  __shared__ int srcRow[BM];
  __shared__ int outRow[BM];

  // block -> (expert, row-tile)
  int t = (int)blockIdx.x;
  int ex = -1, trow = 0, cnt = 0, accT = 0;
#pragma unroll
  for (int i = 0; i < N_EXP; ++i) {
    int c = hdr[i];
    int nt = (c + BM - 1) / BM;
    if (ex < 0 && t < accT + nt) { ex = i; trow = t - accT; cnt = c; }
    accT += nt;
  }
  if (ex < 0) return;
  int row0 = hdr[8 + ex] + trow * BM;
  int rows = min(BM, cnt - trow * BM);

  const int tt = threadIdx.x;
  if (tt < BM) {
    int rr = min(tt, rows - 1);       // tail: duplicate last valid row, masked at store
    int e = perm[row0 + rr];
    outRow[tt] = e;
    srcRow[tt] = index[e];
  }
  __syncthreads();

  // stage A: gather 64 rows x 256 f32 -> bf16 LDS (each wave = 1 row/iter, coalesced 1KB)
#pragma unroll
  for (int i = 0; i < 16; ++i) {
    int lin = i * 256 + tt;
    int r = lin >> 6;
    int c4 = lin & 63;
    const float4 v = ((const float4*)(x + (size_t)srcRow[r] * D_DIM))[c4];
    ushort4 o;
    o.x = f2bf(v.x); o.y = f2bf(v.y); o.z = f2bf(v.z); o.w = f2bf(v.w);
    *(ushort4*)&lA[r * LDK + c4 * 4] = o;
  }
  __syncthreads();

  const int w = tt >> 6, lane = tt & 63, quad = lane >> 4, l16 = lane & 15;

  // wave w owns cols [w*64, w*64+64): B reads disjoint across waves (W[ex] read once/block)
  f32x4 acc[4][4];
#pragma unroll
  for (int mt = 0; mt < 4; ++mt)
#pragma unroll
    for (int nt = 0; nt < 4; ++nt) acc[mt][nt] = (f32x4){0.f, 0.f, 0.f, 0.f};

#pragma unroll
  for (int ks = 0; ks < 8; ++ks) {
    int k0 = ks * 32 + quad * 8;
    bf16x8 a[4], b[4];
#pragma unroll
    for (int mt = 0; mt < 4; ++mt)
      a[mt] = *(const bf16x8*)&lA[(mt * 16 + l16) * LDK + k0];
#pragma unroll
    for (int nt = 0; nt < 4; ++nt) {
      int col = w * 64 + nt * 16 + l16;   // W row (output col)
      if (PRE) {
        b[nt] = *(const bf16x8*)&Wbf[((size_t)ex * D_DIM + col) * D_DIM + k0];
      } else {
        const float* wp = W + ((size_t)ex * D_DIM + col) * D_DIM + k0;
        float4 v0 = ((const float4*)wp)[0];
        float4 v1 = ((const float4*)wp)[1];
        bf16x8 bb;
        bb[0] = (short)f2bf(v0.x); bb[1] = (short)f2bf(v0.y);
        bb[2] = (short)f2bf(v0.z); bb[3] = (short)f2bf(v0.w);
        bb[4] = (short)f2bf(v1.x); bb[5] = (short)f2bf(v1.y);
        bb[6] = (short)f2bf(v1.z); bb[7] = (short)f2bf(v1.w);
        b[nt] = bb;
      }
    }
#pragma unroll
    for (int mt = 0; mt < 4; ++mt)
#pragma unroll
      for (int nt = 0; nt < 4; ++nt)
        acc[mt][nt] = __builtin_amdgcn_mfma_f32_16x16x32_bf16(a[mt], b[nt], acc[mt][nt], 0, 0, 0);
  }

  // epilogue: C/D layout col=lane&15, row=quad*4+reg (m89-verified)
#pragma unroll
  for (int nt = 0; nt < 4; ++nt) {
    int col = w * 64 + nt * 16 + l16;
    float bv = bias[ex * D_DIM + col];
#pragma unroll
    for (int mt = 0; mt < 4; ++mt) {
#pragma unroll
      for (int r = 0; r < 4; ++r) {
        int rl = mt * 16 + quad * 4 + r;
        if (rl < rows)
          out[(size_t)outRow[rl] * D_DIM + col] = acc[mt][nt][r] + bv;
      }
    }
  }
}

extern "C" void kernel_launch(void* const* d_in, const int* in_sizes, int n_in,
                              void* d_out, int out_size, void* d_ws, size_t ws_size,
                              hipStream_t stream) {
  const float* x     = (const float*)d_in[0];
  const float* W     = (const float*)d_in[1];
  const float* bias  = (const float*)d_in[2];
  const int*   index = (const int*)d_in[3];
  const void*  masks = d_in[4];
  float* out = (float*)d_out;

  int* hdr = (int*)d_ws;
  const size_t wbfB  = (size_t)N_EXP * D_DIM * D_DIM * 2;  // 655360
  const size_t permB = (size_t)E_TOT * 4;                  // 1.2 MB
  const size_t bcB   = (size_t)NB_CNT * N_EXP * 4;         // 23.4 KB

  bool pre = (ws_size >= 1024 + wbfB + permB + 2 * bcB);
  size_t off = 1024;
  unsigned short* Wbf = nullptr;
  if (pre) { Wbf = (unsigned short*)((char*)d_ws + off); off += wbfB; }
  int* perm = (int*)((char*)d_ws + off); off += permB;
  int* bc   = (int*)((char*)d_ws + off); off += bcB;
  int* bb   = (int*)((char*)d_ws + off);

  hipMemsetAsync(d_ws, 0, 1024, stream);
  detect_kernel<<<256, 256, 0, stream>>>((const unsigned int*)masks, hdr);
  count_kernel<<<NB_CNT, 256, 0, stream>>>(masks, hdr, bc);
  scan_kernel<<<1, 256, 0, stream>>>(bc, hdr, bb);
  if (pre) convw_kernel<<<(N_EXP * D_DIM * D_DIM / 4 + 255) / 256, 256, 0, stream>>>(W, Wbf);
  scatter_kernel<<<NB_CNT, 256, 0, stream>>>(masks, hdr, bb, perm);
  if (pre)
    gemm_kernel<true><<<MAX_TILES, 256, 0, stream>>>(x, W, Wbf, bias, index, hdr, perm, out);
  else
    gemm_kernel<false><<<MAX_TILES, 256, 0, stream>>>(x, W, Wbf, bias, index, hdr, perm, out);
}